// Round 6
// baseline (125.578 us; speedup 1.0000x reference)
//
#include <hip/hip_runtime.h>
#include <stdint.h>

typedef __attribute__((ext_vector_type(8))) short short8v;
typedef __attribute__((ext_vector_type(4))) float float4v;

__device__ __forceinline__ unsigned short f32_to_bf16(float f) {
    union { float f; uint32_t u; } v; v.f = f;
    uint32_t u = v.u;
    u += 0x7FFFu + ((u >> 16) & 1u);
    return (unsigned short)(u >> 16);
}

#define T_LEN 4096
#define C_DIM 1024
#define HSZ 64

// ---------------- kernel 0: W -> Wt (bf16, transposed [192][1024]) ----------------
__global__ void wt_kernel(const float* __restrict__ Wq, const float* __restrict__ Wk,
                          const float* __restrict__ Wv, unsigned short* __restrict__ Wt) {
    int tid = blockIdx.x * blockDim.x + threadIdx.x;   // 0 .. 3*65536-1
    int m   = tid >> 16;
    int rem = tid & 65535;
    int kk  = rem >> 6;
    int col = rem & 63;
    const float* W = (m == 0) ? Wq : ((m == 1) ? Wk : Wv);
    Wt[(size_t)m * 65536 + (size_t)col * 1024 + kk] = f32_to_bf16(W[(size_t)kk * 64 + col]);
}

// ---------------- kernel 1: fused QKV projection ----------------
// q, k written [B*T][64] row-major; v written TRANSPOSED: vT[b][d][t] ([B][64][4096])
#define XLD 1032   // 1024 + 8 pad

__global__ __launch_bounds__(256) void qkv_kernel(
    const float* __restrict__ x, const unsigned short* __restrict__ Wt,
    unsigned short* __restrict__ qo, unsigned short* __restrict__ ko,
    unsigned short* __restrict__ vto)
{
    __shared__ __align__(16) unsigned short xs[16 * XLD];
    const int tid  = threadIdx.x;
    const int row0 = blockIdx.x * 16;

    #pragma unroll
    for (int i = 0; i < 16; ++i) {
        int f   = i * 256 + tid;           // float4 index, 4096 total
        int row = f >> 8, c4 = f & 255;
        const float4 val = *((const float4*)x + (size_t)(row0 + row) * 256 + c4);
        union { unsigned short s[4]; uint64_t u; } pk;
        pk.s[0] = f32_to_bf16(val.x); pk.s[1] = f32_to_bf16(val.y);
        pk.s[2] = f32_to_bf16(val.z); pk.s[3] = f32_to_bf16(val.w);
        *(uint64_t*)(&xs[row * XLD + c4 * 4]) = pk.u;
    }
    __syncthreads();

    const int wave = tid >> 6, lane = tid & 63;
    const int g = lane >> 4, c = lane & 15;

    float4v acc0 = {0,0,0,0}, acc1 = {0,0,0,0}, acc2 = {0,0,0,0};
    #pragma unroll 4
    for (int ks = 0; ks < 32; ++ks) {
        const int koff = ks * 32 + g * 8;
        short8v a  = *(const short8v*)(&xs[c * XLD + koff]);
        short8v b0 = *(const short8v*)(&Wt[(size_t)((wave*3+0)*16 + c) * 1024 + koff]);
        short8v b1 = *(const short8v*)(&Wt[(size_t)((wave*3+1)*16 + c) * 1024 + koff]);
        short8v b2 = *(const short8v*)(&Wt[(size_t)((wave*3+2)*16 + c) * 1024 + koff]);
        acc0 = __builtin_amdgcn_mfma_f32_16x16x32_bf16(a, b0, acc0, 0, 0, 0);
        acc1 = __builtin_amdgcn_mfma_f32_16x16x32_bf16(a, b1, acc1, 0, 0, 0);
        acc2 = __builtin_amdgcn_mfma_f32_16x16x32_bf16(a, b2, acc2, 0, 0, 0);
    }

    float4v accs[3] = {acc0, acc1, acc2};
    #pragma unroll
    for (int t = 0; t < 3; ++t) {
        int ct = wave * 3 + t;
        int m = ct >> 2, hcol = (ct & 3) * 16 + c;
        if (m == 2) {
            // vT[b][hcol][t_global]
            #pragma unroll
            for (int j = 0; j < 4; ++j) {
                int r = row0 + g * 4 + j;
                vto[((size_t)(r >> 12) * 64 + hcol) * 4096 + (r & 4095)] = f32_to_bf16(accs[t][j]);
            }
        } else {
            unsigned short* dst = (m == 0) ? qo : ko;
            float sc = (m == 0) ? 0.125f : 1.0f;   // fold 1/sqrt(64) into q
            #pragma unroll
            for (int j = 0; j < 4; ++j)
                dst[(size_t)(row0 + g * 4 + j) * 64 + hcol] = f32_to_bf16(accs[t][j] * sc);
        }
    }
}

// ---------------- kernel 2: causal flash attention ----------------
// 512 equal-work blocks: block (batch, p, h) owns the h-th 16-row half of
// q-strip p AND of q-strip 127-p. 8 waves = 8 KV-slices (mod 8) over both
// strips (sequential, two online-softmax states). ntA+ntB ~ 65 tiles const.
#define PLD 72

// one strip's slice-pass; body = R5-verified tile body (t += 8)
__device__ __forceinline__ void strip_pass(
    const unsigned short* __restrict__ ki, const unsigned short* __restrict__ vt,
    size_t bo, int rbase, int nt, int s, int g, int c,
    unsigned short* Pw, short8v qf0, short8v qf1,
    float4v (&acc)[4], float (&mrow)[4], float (&lsum)[4])
{
    for (int t = s; t < nt; t += 8) {
        const int s0 = t * 64;

        // ---- S = Q K^T : B-frags straight from global K (L2-resident) ----
        float4v sa[4];
        #pragma unroll
        for (int ct = 0; ct < 4; ++ct) {
            const unsigned short* krow = ki + bo + (size_t)(s0 + ct * 16 + c) * 64;
            short8v b0 = *(const short8v*)(krow +  0 + g * 8);
            short8v b1 = *(const short8v*)(krow + 32 + g * 8);
            float4v z = {0, 0, 0, 0};
            z = __builtin_amdgcn_mfma_f32_16x16x32_bf16(qf0, b0, z, 0, 0, 0);
            sa[ct] = __builtin_amdgcn_mfma_f32_16x16x32_bf16(qf1, b1, z, 0, 0, 0);
        }

        // ---- issue first half of vT B-frags (latency hides under softmax) ----
        short8v vf0[4];
        #pragma unroll
        for (int ct = 0; ct < 4; ++ct)
            vf0[ct] = *(const short8v*)(vt + bo + (size_t)(ct * 16 + c) * 4096 + s0 + 0 + g * 8);

        // ---- causal mask ----
        if (s0 + 63 > rbase) {
            #pragma unroll
            for (int ct = 0; ct < 4; ++ct)
                #pragma unroll
                for (int j = 0; j < 4; ++j)
                    if (s0 + ct * 16 + c > rbase + g * 4 + j) sa[ct][j] = -3e38f;
        }

        // ---- online softmax (cross-lane sum deferred) ----
        #pragma unroll
        for (int j = 0; j < 4; ++j) {
            float mx = fmaxf(fmaxf(sa[0][j], sa[1][j]), fmaxf(sa[2][j], sa[3][j]));
            #pragma unroll
            for (int sh = 1; sh < 16; sh <<= 1) mx = fmaxf(mx, __shfl_xor(mx, sh, 64));
            const float nm = fmaxf(mrow[j], mx);
            const float al = __expf(mrow[j] - nm);
            mrow[j] = nm;
            float ps = 0.f;
            #pragma unroll
            for (int ct = 0; ct < 4; ++ct) {
                float p = __expf(sa[ct][j] - nm);
                sa[ct][j] = p;
                ps += p;
            }
            lsum[j] = lsum[j] * al + ps;
            #pragma unroll
            for (int ct = 0; ct < 4; ++ct) acc[ct][j] *= al;
        }

        // ---- P (D-layout) -> per-wave LDS -> A-fragment layout ----
        #pragma unroll
        for (int ct = 0; ct < 4; ++ct)
            #pragma unroll
            for (int j = 0; j < 4; ++j)
                Pw[(g * 4 + j) * PLD + ct * 16 + c] = f32_to_bf16(sa[ct][j]);

        // ---- second half of vT B-frags (hides under P roundtrip) ----
        short8v vf1[4];
        #pragma unroll
        for (int ct = 0; ct < 4; ++ct)
            vf1[ct] = *(const short8v*)(vt + bo + (size_t)(ct * 16 + c) * 4096 + s0 + 32 + g * 8);

        short8v pa0 = *(const short8v*)(&Pw[c * PLD +  0 + g * 8]);
        short8v pa1 = *(const short8v*)(&Pw[c * PLD + 32 + g * 8]);

        // ---- O += P V ----
        #pragma unroll
        for (int ct = 0; ct < 4; ++ct)
            acc[ct] = __builtin_amdgcn_mfma_f32_16x16x32_bf16(pa0, vf0[ct], acc[ct], 0, 0, 0);
        #pragma unroll
        for (int ct = 0; ct < 4; ++ct)
            acc[ct] = __builtin_amdgcn_mfma_f32_16x16x32_bf16(pa1, vf1[ct], acc[ct], 0, 0, 0);
    }
}

__global__ __launch_bounds__(512) void attn_kernel(
    const unsigned short* __restrict__ qi, const unsigned short* __restrict__ ki,
    const unsigned short* __restrict__ vt, float* __restrict__ out)
{
    __shared__ __align__(16) unsigned short Ps[8][16 * PLD];   // per-wave P buffer
    __shared__ float CombO[2][7][16][64];                      // [strip][slot][row][col]
    __shared__ float CombM[2][7][16];
    __shared__ float CombL[2][7][16];

    const int tid  = threadIdx.x;
    const int wave = tid >> 6, lane = tid & 63;
    const int g = lane >> 4, c = lane & 15;

    const int bid   = (int)blockIdx.x;
    const int batch = bid >> 7;
    const int j2    = bid & 127;
    const int p     = j2 >> 1, h = j2 & 1;
    const int rbA   = p * 32 + h * 16;
    const int rbB   = (127 - p) * 32 + h * 16;
    const size_t bo = (size_t)batch * T_LEN * HSZ;

    short8v qfA0 = *(const short8v*)(qi + bo + (size_t)(rbA + c) * 64 +  0 + g * 8);
    short8v qfA1 = *(const short8v*)(qi + bo + (size_t)(rbA + c) * 64 + 32 + g * 8);
    short8v qfB0 = *(const short8v*)(qi + bo + (size_t)(rbB + c) * 64 +  0 + g * 8);
    short8v qfB1 = *(const short8v*)(qi + bo + (size_t)(rbB + c) * 64 + 32 + g * 8);

    float4v accA[4], accB[4];
    float mA[4], lA[4], mB[4], lB[4];
    #pragma unroll
    for (int i = 0; i < 4; ++i) {
        accA[i] = (float4v){0,0,0,0}; accB[i] = (float4v){0,0,0,0};
        mA[i] = -3e38f; mB[i] = -3e38f; lA[i] = 0.f; lB[i] = 0.f;
    }

    const int ntA = ((rbA + 15) >> 6) + 1;
    const int ntB = ((rbB + 15) >> 6) + 1;
    unsigned short* Pw = &Ps[wave][0];

    strip_pass(ki, vt, bo, rbA, ntA, wave, g, c, Pw, qfA0, qfA1, accA, mA, lA);
    strip_pass(ki, vt, bo, rbB, ntB, wave, g, c, Pw, qfB0, qfB1, accB, mB, lB);

    // per-wave: reduce row sums across the 16 c-lanes (both strips)
    #pragma unroll
    for (int j = 0; j < 4; ++j) {
        float la = lA[j], lb = lB[j];
        #pragma unroll
        for (int sh = 1; sh < 16; sh <<= 1) { la += __shfl_xor(la, sh, 64); lb += __shfl_xor(lb, sh, 64); }
        lA[j] = la; lB[j] = lb;
    }

    // contributions: strip A combined by wave 0 (slots = wave-1 for waves 1..7),
    //                strip B combined by wave 7 (slots = wave  for waves 0..6)
    if (wave != 0) {
        const int s = wave - 1;
        #pragma unroll
        for (int ct = 0; ct < 4; ++ct)
            #pragma unroll
            for (int j = 0; j < 4; ++j)
                CombO[0][s][g * 4 + j][ct * 16 + c] = accA[ct][j];
        if (c == 0) {
            #pragma unroll
            for (int j = 0; j < 4; ++j) { CombM[0][s][g * 4 + j] = mA[j]; CombL[0][s][g * 4 + j] = lA[j]; }
        }
    }
    if (wave != 7) {
        const int s = wave;
        #pragma unroll
        for (int ct = 0; ct < 4; ++ct)
            #pragma unroll
            for (int j = 0; j < 4; ++j)
                CombO[1][s][g * 4 + j][ct * 16 + c] = accB[ct][j];
        if (c == 0) {
            #pragma unroll
            for (int j = 0; j < 4; ++j) { CombM[1][s][g * 4 + j] = mB[j]; CombL[1][s][g * 4 + j] = lB[j]; }
        }
    }
    __syncthreads();

    if (wave == 0 || wave == 7) {
        const int st = (wave == 0) ? 0 : 1;
        const int rb = (wave == 0) ? rbA : rbB;
        float* mw = (wave == 0) ? mA : mB;
        float* lw = (wave == 0) ? lA : lB;
        float4v* aw = (wave == 0) ? accA : accB;

        float a0[4], as[7][4], linv[4];
        #pragma unroll
        for (int j = 0; j < 4; ++j) {
            const int r = g * 4 + j;
            float M = mw[j];
            #pragma unroll
            for (int s = 0; s < 7; ++s) M = fmaxf(M, CombM[st][s][r]);
            a0[j] = __expf(mw[j] - M);
            float lt = lw[j] * a0[j];
            #pragma unroll
            for (int s = 0; s < 7; ++s) {
                as[s][j] = __expf(CombM[st][s][r] - M);
                lt += as[s][j] * CombL[st][s][r];
            }
            linv[j] = 1.0f / lt;
        }
        #pragma unroll
        for (int ct = 0; ct < 4; ++ct)
            #pragma unroll
            for (int j = 0; j < 4; ++j) {
                const int r = g * 4 + j;
                float o = aw[ct][j] * a0[j];
                #pragma unroll
                for (int s = 0; s < 7; ++s)
                    o += as[s][j] * CombO[st][s][r][ct * 16 + c];
                out[bo + (size_t)(rb + r) * 64 + ct * 16 + c] = o * linv[j];
            }
    }
}

extern "C" void kernel_launch(void* const* d_in, const int* in_sizes, int n_in,
                              void* d_out, int out_size, void* d_ws, size_t ws_size,
                              hipStream_t stream) {
    const float* x  = (const float*)d_in[0];
    const float* Wq = (const float*)d_in[1];
    const float* Wk = (const float*)d_in[2];
    const float* Wv = (const float*)d_in[3];

    unsigned short* Wt = (unsigned short*)d_ws;                        // 384 KiB
    unsigned short* q  = (unsigned short*)((char*)d_ws + (size_t)3 * 65536 * 2);
    unsigned short* k  = q + (size_t)4 * T_LEN * HSZ;
    unsigned short* vT = k + (size_t)4 * T_LEN * HSZ;                  // [B][64][4096]
    float* out = (float*)d_out;

    hipLaunchKernelGGL(wt_kernel,  dim3(768), dim3(256), 0, stream, Wq, Wk, Wv, Wt);
    hipLaunchKernelGGL(qkv_kernel, dim3(1024), dim3(256), 0, stream, x, Wt, q, k, vT);
    hipLaunchKernelGGL(attn_kernel, dim3(512), dim3(512), 0, stream, q, k, vT, out);
}